// Round 8
// baseline (298.618 us; speedup 1.0000x reference)
//
#include <hip/hip_runtime.h>

// RowAttentionWithPairBias  (B=1, M=128, N=256, C_IN=256, C_PAIR=128, H=8, C=32)
// Harness contract (established r0-r3): inputs fp32, OUTPUT fp32 (bf16-level
// tolerance). Internal compute: bf16 MFMA, fp32 accumulation.
// R4: k_qkvg/k_final use m97-style staged GEMM core: global_load_lds width=16,
// XOR-swizzled LDS ([row][chunk^(row&7)]) -> ds_read_b128 conflict-free (2-way).
// R5: exp2-space softmax (q pre-scaled by log2e), deferred normalization,
// transposed gate gT[m][o][i], no barriers in k_attn (P wave-private).
// R6: slab-merged k_attn REGRESSED (132us; serial HBM chains) -> reverted.
// R7: zero-shuffle softmax (no-max exp2 + ones-MFMA row sum).
// R8: DMA-staged K/V in LDS: 108 -> 57us (latency wall broken).
// R9: correct K/V swizzles (conflicts 6.8M -> 1.6M), stage-once: 51.6us.
//     Profile: NOTHING saturated; occupancy 17.6% (2 blocks/CU, LDS-bound).
// R10/R11: container failed twice (infra suspected). R11 audit: all addresses
//     in-bounds, DMA dests wave-uniform, peak live regs ~160 <= (256,3) cap,
//     no divergent barriers. RESUBMITTING R11 unchanged. If it fails a third
//     time, fall back to R9-exact to disambiguate kernel vs infra.
// R11 changes vs R9:
//   - V staging dropped (V direct from L1/L2): LDS 66.5 -> 50.2 KB -> 3 blk/CU.
//   - q for all 4 slabs prefetched before staging barrier (16 VGPR).
//   - bias SINGLE-buffer bbuf[16] (64 VGPR): slab0 loads overlap DMA drain;
//     slab s+1 loads issued after slab-s exp2 (old values dead -> regs reused;
//     hidden under gate-prefetch + PV + stores).
//   - bias enters QK^T as MFMA C-operand FROM REGISTERS (R5's failure was
//     in-flight-load operands; register operands are free).
// Verified fragment layouts (learn_hip m89/m91/m92/m120), v_mfma_f32_16x16x32_bf16:
//   A: lane holds A[m=lane&15][k=(lane>>4)*8 + j], j=0..7
//   B: lane holds B[k=(lane>>4)*8 + j][n=lane&15]
//   C/D: col = lane&15, row = (lane>>4)*4 + reg

typedef unsigned short u16;
typedef unsigned int   u32;
typedef __attribute__((ext_vector_type(8))) __bf16 bf16x8;
typedef __attribute__((ext_vector_type(4))) float  f32x4;
typedef __attribute__((ext_vector_type(4))) u16    u16x4;

#define DEV __device__ __forceinline__

#define LOG2E 1.4426950408889634f

DEV float bf2f(u16 s) {
    u32 u = ((u32)s) << 16;
    float f;
    __builtin_memcpy(&f, &u, 4);
    return f;
}
DEV u16 f2bf(float f) {
    __bf16 h = (__bf16)f;              // native RNE convert (m240: don't hand-roll)
    u16 u;
    __builtin_memcpy(&u, &h, 2);
    return u;
}

// async global->LDS, 16 B per lane; LDS dest wave-uniform base + lane*16
#define GLD_LDS16(gp, lp)                                                           \
    __builtin_amdgcn_global_load_lds(                                               \
        (const __attribute__((address_space(1))) u32*)(const void*)(gp),            \
        (__attribute__((address_space(3))) u32*)(void*)(lp), 16, 0, 0)

// ---------------------------------------------------------------- transpose W (fp32 -> bf16)
// WT[1024][256]: rows 0-255 Wq^T, 256-511 Wk^T, 512-767 Wv^T, 768-1023 Wgate^T
// WfT[256][256] = Wfinal^T
__global__ void k_transpose(const float* __restrict__ Wq, const float* __restrict__ Wk,
                            const float* __restrict__ Wv, const float* __restrict__ Wg,
                            const float* __restrict__ Wf,
                            u16* __restrict__ WT, u16* __restrict__ WfT) {
    int idx = blockIdx.x * 256 + threadIdx.x;
    if (idx < 1024 * 256) {
        int gcol = idx >> 8, p = idx & 255;
        int sel = gcol >> 8, c = gcol & 255;
        const float* W = sel == 0 ? Wq : sel == 1 ? Wk : sel == 2 ? Wv : Wg;
        WT[idx] = f2bf(W[p * 256 + c]);
    } else {
        int j = idx - 1024 * 256;            // [0, 65536)
        int d = j >> 8, hc = j & 255;
        WfT[j] = f2bf(Wf[hc * 256 + d]);
    }
}

// ---------------------------------------------------------------- LayerNorm 1
// x1d [32768][256] fp32 -> x1 [32768][256] bf16.  One wave per row.
__global__ __launch_bounds__(256) void k_ln1(const float* __restrict__ x,
                                             const float* __restrict__ gg,
                                             const float* __restrict__ bb,
                                             u16* __restrict__ y) {
    int lane = threadIdx.x & 63, wave = threadIdx.x >> 6;
    int row = blockIdx.x * 4 + wave;
    float4 xv = *(const float4*)(x + row * 256 + lane * 4);
    float v0 = xv.x, v1 = xv.y, v2 = xv.z, v3 = xv.w;
    float s  = v0 + v1 + v2 + v3;
    float s2 = v0*v0 + v1*v1 + v2*v2 + v3*v3;
    #pragma unroll
    for (int msk = 32; msk; msk >>= 1) {
        s  += __shfl_xor(s,  msk, 64);
        s2 += __shfl_xor(s2, msk, 64);
    }
    float mu  = s * (1.0f / 256.0f);
    float var = s2 * (1.0f / 256.0f) - mu * mu;
    float rs  = rsqrtf(var + 1e-5f);
    float4 gv = *(const float4*)(gg + lane * 4);
    float4 bv = *(const float4*)(bb + lane * 4);
    ushort4 o;
    o.x = f2bf((v0 - mu) * rs * gv.x + bv.x);
    o.y = f2bf((v1 - mu) * rs * gv.y + bv.y);
    o.z = f2bf((v2 - mu) * rs * gv.z + bv.z);
    o.w = f2bf((v3 - mu) * rs * gv.w + bv.w);
    *(ushort4*)(y + row * 256 + lane * 4) = o;
}

// ---------------------------------------------------------------- LN2 + pair bias
// x2d [65536][128] fp32 -> biasT[h][j][i] fp32, PRE-SCALED by log2e
// (biasT[h*65536 + j*256 + i]; transposed so k_attn loads float4 over i)
__global__ __launch_bounds__(256) void k_ln2bias(const float* __restrict__ x2,
                                                 const float* __restrict__ gg,
                                                 const float* __restrict__ bb,
                                                 const float* __restrict__ W2d,
                                                 float* __restrict__ biasT) {
    int lane = threadIdx.x & 63, wave = threadIdx.x >> 6;
    int b = blockIdx.x;
    int i = (b >> 8) * 4 + wave;                     // [0,256)
    int j = b & 255;                                 // [0,256)
    int row = i * 256 + j;
    float2 xv = *(const float2*)(x2 + row * 128 + lane * 2);
    float v0 = xv.x, v1 = xv.y;
    float s = v0 + v1, s2 = v0*v0 + v1*v1;
    #pragma unroll
    for (int msk = 32; msk; msk >>= 1) {
        s  += __shfl_xor(s,  msk, 64);
        s2 += __shfl_xor(s2, msk, 64);
    }
    float mu  = s * (1.0f / 128.0f);
    float var = s2 * (1.0f / 128.0f) - mu * mu;
    float rs  = rsqrtf(var + 1e-5f);
    float2 gv = *(const float2*)(gg + lane * 2);
    float2 bv = *(const float2*)(bb + lane * 2);
    float xn0 = (v0 - mu) * rs * gv.x + bv.x;
    float xn1 = (v1 - mu) * rs * gv.y + bv.y;
    int p0 = lane * 2;
    float4 w0a = *(const float4*)(W2d + p0 * 8);
    float4 w0b = *(const float4*)(W2d + p0 * 8 + 4);
    float4 w1a = *(const float4*)(W2d + (p0 + 1) * 8);
    float4 w1b = *(const float4*)(W2d + (p0 + 1) * 8 + 4);
    float p[8];
    p[0] = xn0 * w0a.x + xn1 * w1a.x;
    p[1] = xn0 * w0a.y + xn1 * w1a.y;
    p[2] = xn0 * w0a.z + xn1 * w1a.z;
    p[3] = xn0 * w0a.w + xn1 * w1a.w;
    p[4] = xn0 * w0b.x + xn1 * w1b.x;
    p[5] = xn0 * w0b.y + xn1 * w1b.y;
    p[6] = xn0 * w0b.z + xn1 * w1b.z;
    p[7] = xn0 * w0b.w + xn1 * w1b.w;
    #pragma unroll
    for (int hh = 0; hh < 8; hh++)
        #pragma unroll
        for (int msk = 32; msk; msk >>= 1)
            p[hh] += __shfl_xor(p[hh], msk, 64);
    if (lane == 0) {
        #pragma unroll
        for (int hh = 0; hh < 8; hh++)
            biasT[hh * 65536 + j * 256 + i] = p[hh] * LOG2E;
    }
}

// ---------------------------------------------------------------- staged 128x128 GEMM core
// C[128x128 tile] = X[rowbase..+127][0..K) * WTb[colbase..+127][0..K)^T
// As/Bs: [128][64] u16, chunk-swizzled: phys chunk p of row r holds logical
// chunk p ^ (r&7)  (chunk = 8 u16 = 16 B).  BK=64, 2-barrier K-loop.
DEV void gemm128_core(const u16* __restrict__ X, const u16* __restrict__ WTb,
                      int rowbase, int colbase, int K,
                      u16* As, u16* Bs, f32x4 acc[4][4], int lane, int wave) {
    int l8 = lane & 7, r8 = lane >> 3;       // chunk-in-row, row-in-segment (8 rows/instr)
    int gchunk = l8 ^ (r8 & 7);              // xor swizzle: phys chunk l8 <- logical chunk l8^r8
    int lrow = lane & 15, quad = lane >> 4;
    int wr = (wave >> 1) * 64, wc = (wave & 1) * 64;

    for (int kk = 0; kk < K; kk += 64) {
        #pragma unroll
        for (int i = 0; i < 4; i++) {
            int s = wave * 4 + i;                            // segment 0..15 (8 rows each)
            const u16* g = X + (rowbase + s * 8 + r8) * K + kk + gchunk * 8;
            GLD_LDS16(g, As + s * 512);
        }
        #pragma unroll
        for (int i = 0; i < 4; i++) {
            int s = wave * 4 + i;
            const u16* g = WTb + (colbase + s * 8 + r8) * K + kk + gchunk * 8;
            GLD_LDS16(g, Bs + s * 512);
        }
        __syncthreads();                                     // waits vmcnt(0) for the DMA
        #pragma unroll
        for (int k2 = 0; k2 < 64; k2 += 32) {
            int cidx = (k2 >> 3) + quad;                     // logical chunk 0..7
            bf16x8 af[4], bf[4];
            #pragma unroll
            for (int t = 0; t < 4; t++) {
                int R = wr + t * 16 + lrow;
                af[t] = *(const bf16x8*)(As + R * 64 + ((cidx ^ (R & 7)) << 3));
            }
            #pragma unroll
            for (int t = 0; t < 4; t++) {
                int R = wc + t * 16 + lrow;
                bf[t] = *(const bf16x8*)(Bs + R * 64 + ((cidx ^ (R & 7)) << 3));
            }
            #pragma unroll
            for (int i = 0; i < 4; i++)
                #pragma unroll
                for (int j = 0; j < 4; j++)
                    acc[i][j] = __builtin_amdgcn_mfma_f32_16x16x32_bf16(af[i], bf[j], acc[i][j], 0, 0, 0);
        }
        __syncthreads();
    }
}

// ---------------------------------------------------------------- QKVG projection
// X=x1 [32768][256] @ WT -> cols 0-255 q (scaled by log2e/sqrt(C)), 256-511 k,
// 512-767 v (stored transposed vt[m][o][i]), 768-1023 gate (sigmoid applied,
// stored transposed gT[m][o][i]).
// grid (256, 8), block 256.  Block tile 128x128, wave tile 64x64.
__global__ __launch_bounds__(256) void k_qkvg(const u16* __restrict__ X, const u16* __restrict__ WT,
                                              u16* __restrict__ q, u16* __restrict__ kb,
                                              u16* __restrict__ vt, u16* __restrict__ gt,
                                              const float* __restrict__ bgate) {
    __shared__ u16 As[128 * 64];
    __shared__ u16 Bs[128 * 64];
    int lane = threadIdx.x & 63, wave = threadIdx.x >> 6;
    int rowbase = blockIdx.x * 128;
    int colbase = blockIdx.y * 128;
    f32x4 acc[4][4];
    #pragma unroll
    for (int i = 0; i < 4; i++)
        #pragma unroll
        for (int j = 0; j < 4; j++)
            acc[i][j] = (f32x4){0.f, 0.f, 0.f, 0.f};
    gemm128_core(X, WT, rowbase, colbase, 256, As, Bs, acc, lane, wave);
    int lrow = lane & 15, quad = lane >> 4;
    int wrb = rowbase + (wave >> 1) * 64, wcb = colbase + (wave & 1) * 64;
    int which = blockIdx.y >> 1;          // uniform per block: 0=q 1=k 2=v 3=gate
    #pragma unroll
    for (int it = 0; it < 4; it++)
        #pragma unroll
        for (int jt = 0; jt < 4; jt++) {
            int grow0 = wrb + it * 16 + quad * 4;      // +r stays in same 256-row band
            int gcol  = wcb + jt * 16 + lrow;
            int o = gcol & 255;
            if (which == 0) {
                #pragma unroll
                for (int r = 0; r < 4; r++)
                    q[(grow0 + r) * 256 + o] = f2bf(acc[it][jt][r] * (0.17677669529663687f * LOG2E));
            } else if (which == 1) {
                #pragma unroll
                for (int r = 0; r < 4; r++)
                    kb[(grow0 + r) * 256 + o] = f2bf(acc[it][jt][r]);
            } else if (which == 2) {
                int mm = grow0 >> 8, ii = grow0 & 255;
                ushort4 pv;
                pv.x = f2bf(acc[it][jt][0]);
                pv.y = f2bf(acc[it][jt][1]);
                pv.z = f2bf(acc[it][jt][2]);
                pv.w = f2bf(acc[it][jt][3]);
                *(ushort4*)(vt + (mm * 256 + o) * 256 + ii) = pv;
            } else {
                int mm = grow0 >> 8, ii = grow0 & 255;
                float bgo = bgate[o];
                ushort4 pv;
                pv.x = f2bf(1.0f / (1.0f + __expf(-(acc[it][jt][0] + bgo))));
                pv.y = f2bf(1.0f / (1.0f + __expf(-(acc[it][jt][1] + bgo))));
                pv.z = f2bf(1.0f / (1.0f + __expf(-(acc[it][jt][2] + bgo))));
                pv.w = f2bf(1.0f / (1.0f + __expf(-(acc[it][jt][3] + bgo))));
                *(ushort4*)(gt + (mm * 256 + o) * 256 + ii) = pv;
            }
        }
}

// ---------------------------------------------------------------- attention
// grid (m=128, h=8), block 256 (4 waves).  K staged ONCE per block (LDS);
// V direct from L1/L2 (R7-proven addressing).  Each wave: 4 slabs of 16 q-rows.
// LDS (u16 idx): Ks [0,8192) = K [256 j][32 cc], phys chunk = q ^ ((j>>1)&3)
//                P  [8192,25088) = per-wave padded [16][264]
// 50176 B -> 3 blocks/CU.  Pipelining: q[0..3] + bias slab-0 prefetched before
// the staging barrier; bias slab s+1 issued after slab-s exp2 (old bbuf dead,
// regs reused; hidden under gate-prefetch + PV + stores); bias enters QK^T as
// MFMA C-operand from REGISTERS.
__global__ __launch_bounds__(256, 3) void k_attn(const u16* __restrict__ q, const u16* __restrict__ kb,
                                                 const u16* __restrict__ vt, const u16* __restrict__ gt,
                                                 const float* __restrict__ biasT,
                                                 u16* __restrict__ tmp) {
    __shared__ u16 S[25088];               // 50176 B
    u16* Ks = S;
    int lane = threadIdx.x & 63, wave = threadIdx.x >> 6;
    int lrow = lane & 15, quad = lane >> 4, lk = quad * 8;
    int m = blockIdx.x, h = blockIdx.y;

    const u16* qm  = q  + m * 65536 + h * 32;
    const u16* kbm = kb + m * 65536 + h * 32;
    const u16* vtm = vt + (m * 256 + h * 32) * 256;
    const u16* gtm = gt + (m * 256 + h * 32) * 256;
    u16*       tm  = tmp + m * 65536 + h * 32;
    const float* bh = biasT + h * 65536;
    u16* Pw = S + 8192 + wave * 4224;      // [16][264]

    // ---- q prefetch for all 4 slabs (overlaps K DMA + barrier)
    bf16x8 aq[4];
    #pragma unroll
    for (int s = 0; s < 4; s++)
        aq[s] = *(const bf16x8*)(qm + (s * 64 + wave * 16 + lrow) * 256 + lk);

    // ---- K DMA: 16 segs of 16 j-rows, 4 per wave (swizzle as R9, verified)
    {
        int jl = lane >> 2;
        int qq = (lane & 3) ^ ((lane >> 3) & 3);
        const u16* gK = kbm + jl * 256 + qq * 8;
        #pragma unroll
        for (int t = 0; t < 4; t++) {
            int seg = wave * 4 + t;
            GLD_LDS16(gK + seg * 4096, Ks + seg * 512);
        }
    }

    // ---- bias slab-0 prefetch (overlaps DMA drain); SINGLE buffer (64 VGPR)
    const float* bptr = bh + lrow * 256 + wave * 16 + quad * 4;
    f32x4 bbuf[16];
    #pragma unroll
    for (int jt = 0; jt < 16; jt++)
        bbuf[jt] = *(const f32x4*)(bptr + jt * 4096);

    __syncthreads();                                     // drains DMA (vmcnt 0)

    bf16x8 ones;
    {
        u16 ou = 0x3F80;                   // bf16 1.0
        __bf16 ob;
        __builtin_memcpy(&ob, &ou, 2);
        #pragma unroll
        for (int j = 0; j < 8; j++) ones[j] = ob;
    }

    #pragma unroll
    for (int s = 0; s < 4; s++) {
        int i0 = s * 64 + wave * 16;

        // ---- QK^T from LDS K, bias as C-operand (in regs -> no serialization)
        f32x4 acc[16];
        #pragma unroll
        for (int jt = 0; jt < 16; jt++) {
            int ra = (jt * 16 + lrow) * 32 + ((quad ^ ((lrow >> 1) & 3)) << 3);
            bf16x8 bk = *(const bf16x8*)(Ks + ra);
            acc[jt] = __builtin_amdgcn_mfma_f32_16x16x32_bf16(aq[s], bk, bbuf[jt], 0, 0, 0);
        }

        // ---- exp2 + P write (padded [16][264]; no max: LN-bounded, exp2-safe)
        #pragma unroll
        for (int jt = 0; jt < 16; jt++)
            #pragma unroll
            for (int r = 0; r < 4; r++)
                Pw[(quad * 4 + r) * 264 + jt * 16 + lrow] = f2bf(exp2f(acc[jt][r]));

        // ---- prefetch bias for slab s+1 (bbuf dead after QK^T; regs reused;
        //      loads hide under gate-prefetch + PV + stores)
        if (s < 3) {
            const float* bp = bptr + (s + 1) * 64;
            #pragma unroll
            for (int jt = 0; jt < 16; jt++)
                bbuf[jt] = *(const f32x4*)(bp + jt * 4096);
        }

        // ---- gate prefetch (used at epilogue)
        u16x4 gv4[2];
        #pragma unroll
        for (int ct = 0; ct < 2; ct++)
            gv4[ct] = *(const u16x4*)(gtm + (ct * 16 + lrow) * 256 + i0 + quad * 4);

        // ---- PV + ones-sum: P from LDS, V direct (L1/L2; written by k_qkvg)
        f32x4 oacc[2] = {{0.f,0.f,0.f,0.f}, {0.f,0.f,0.f,0.f}};
        f32x4 osum = {0.f, 0.f, 0.f, 0.f};
        #pragma unroll
        for (int kk2 = 0; kk2 < 256; kk2 += 32) {
            bf16x8 ap = *(const bf16x8*)(Pw + lrow * 264 + kk2 + lk);
            osum = __builtin_amdgcn_mfma_f32_16x16x32_bf16(ap, ones, osum, 0, 0, 0);
            #pragma unroll
            for (int ct = 0; ct < 2; ct++) {
                bf16x8 bv = *(const bf16x8*)(vtm + (ct * 16 + lrow) * 256 + kk2 + lk);
                oacc[ct] = __builtin_amdgcn_mfma_f32_16x16x32_bf16(ap, bv, oacc[ct], 0, 0, 0);
            }
        }

        // ---- 1/sum + gate multiply + store gated output [m,i,h,c]
        float rinv[4];
        #pragma unroll
        for (int r = 0; r < 4; r++)
            rinv[r] = __builtin_amdgcn_rcpf(osum[r]);
        #pragma unroll
        for (int ct = 0; ct < 2; ct++)
            #pragma unroll
            for (int r = 0; r < 4; r++) {
                int i = i0 + quad * 4 + r;
                float gv = bf2f(gv4[ct][r]);
                tm[i * 256 + ct * 16 + lrow] = f2bf(oacc[ct][r] * rinv[r] * gv);
            }
    }
}

// ---------------------------------------------------------------- final projection
// tmp [32768][256] @ WfT + bfinal -> out FP32.  grid (256, 2).
__global__ __launch_bounds__(256) void k_final(const u16* __restrict__ T, const u16* __restrict__ WfT,
                                               const float* __restrict__ bfinal, float* __restrict__ out) {
    __shared__ u16 As[128 * 64];
    __shared__ u16 Bs[128 * 64];
    int lane = threadIdx.x & 63, wave = threadIdx.x >> 6;
    int rowbase = blockIdx.x * 128;
    int colbase = blockIdx.y * 128;
    f32x4 acc[4][4];
    #pragma unroll
    for (int i = 0; i < 4; i++)
        #pragma unroll
        for (int j = 0; j < 4; j++)
            acc[i][j] = (f32x4){0.f, 0.f, 0.f, 0.f};
    gemm128_core(T, WfT, rowbase, colbase, 256, As, Bs, acc, lane, wave);
    int lrow = lane & 15, quad = lane >> 4;
    int wrb = rowbase + (wave >> 1) * 64, wcb = colbase + (wave & 1) * 64;
    #pragma unroll
    for (int it = 0; it < 4; it++)
        #pragma unroll
        for (int jt = 0; jt < 4; jt++)
            #pragma unroll
            for (int r = 0; r < 4; r++) {
                int grow = wrb + it * 16 + quad * 4 + r;
                int gcol = wcb + jt * 16 + lrow;
                out[grow * 256 + gcol] = acc[it][jt][r] + bfinal[gcol];
            }
}

// ---------------------------------------------------------------- launch
extern "C" void kernel_launch(void* const* d_in, const int* in_sizes, int n_in,
                              void* d_out, int out_size, void* d_ws, size_t ws_size,
                              hipStream_t stream) {
    const float* x1d   = (const float*)d_in[0];
    const float* x2d   = (const float*)d_in[1];
    const float* ln1_g = (const float*)d_in[2];
    const float* ln1_b = (const float*)d_in[3];
    const float* ln2_g = (const float*)d_in[4];
    const float* ln2_b = (const float*)d_in[5];
    const float* Wq    = (const float*)d_in[6];
    const float* Wk    = (const float*)d_in[7];
    const float* Wv    = (const float*)d_in[8];
    const float* W2d   = (const float*)d_in[9];
    const float* Wg    = (const float*)d_in[10];
    const float* bg    = (const float*)d_in[11];
    const float* Wf    = (const float*)d_in[12];
    const float* bfin  = (const float*)d_in[13];
    float* out = (float*)d_out;

    char* ws = (char*)d_ws;
    u16*   x1   = (u16*)(ws);                    // 16,777,216 B  (reused as tmp)
    u16*   WT   = (u16*)(ws + 16777216);         //    524,288 B
    u16*   WfT  = (u16*)(ws + 17301504);         //    131,072 B
    float* bias = (float*)(ws + 17432576);       //  2,097,152 B  (biasT[h][j][i], log2e-scaled)
    u16*   qb   = (u16*)(ws + 19529728);         // 16,777,216 B
    u16*   kb   = (u16*)(ws + 36306944);         // 16,777,216 B
    u16*   vtb  = (u16*)(ws + 53084160);         // 16,777,216 B
    u16*   gb   = (u16*)(ws + 69861376);         // 16,777,216 B  (end: 86,638,592)
    u16*   tmp  = x1;                            // x1 dead after k_qkvg

    k_transpose<<<1280, 256, 0, stream>>>(Wq, Wk, Wv, Wg, Wf, WT, WfT);
    k_ln1<<<8192, 256, 0, stream>>>(x1d, ln1_g, ln1_b, x1);
    k_ln2bias<<<16384, 256, 0, stream>>>(x2d, ln2_g, ln2_b, W2d, bias);
    k_qkvg<<<dim3(256, 8), 256, 0, stream>>>(x1, WT, qb, kb, vtb, gb, bg);
    k_attn<<<dim3(128, 8), 256, 0, stream>>>(qb, kb, vtb, gb, bias, tmp);
    k_final<<<dim3(256, 2), 256, 0, stream>>>(tmp, WfT, bfin, out);
}

// Round 9
// 256.505 us; speedup vs baseline: 1.1642x; 1.1642x over previous
//
#include <hip/hip_runtime.h>

// RowAttentionWithPairBias  (B=1, M=128, N=256, C_IN=256, C_PAIR=128, H=8, C=32)
// Harness contract (established r0-r3): inputs fp32, OUTPUT fp32 (bf16-level
// tolerance). Internal compute: bf16 MFMA, fp32 accumulation.
// R4: k_qkvg/k_final use m97-style staged GEMM core: global_load_lds width=16,
// XOR-swizzled LDS ([row][chunk^(row&7)]) -> ds_read_b128 conflict-free (2-way).
// R5: exp2-space softmax (q pre-scaled by log2e), deferred normalization,
// transposed gate gT[m][o][i], no barriers in k_attn (P wave-private).
// R6: slab-merged k_attn REGRESSED (132us; serial HBM chains) -> reverted.
// R7: zero-shuffle softmax (no-max exp2 + ones-MFMA row sum).
// R8: DMA-staged K/V in LDS: 108 -> 57us (latency wall broken).
// R9: correct K/V swizzles (conflicts 6.8M -> 1.6M), stage-once: 51.6us @ 2 blk/CU.
// R11: V-direct (no LDS) REGRESSED 51.6 -> 92.4us: vt evicted from L2 by
//     k_qkvg's 64MB of later writes -> PV loop ate ~900cyc HBM latency per V
//     load. LAW: k_attn loop operands must come from LDS/registers.
// R12 (this round): R9 staging + R11's reg-bias + half-split P for occupancy.
//   - K AND V staged in LDS (R9-verified swizzles, waves 0-1 K / 2-3 V).
//   - P half-split: per slab, 2 phases of 128 j each; P buffer [16][136]
//     (17.4KB total) -> LDS 50176 B -> 3 blocks/CU (R9 was 2).
//   - bias bbuf[8] in regs as QK^T C-operand; prefetched 1 phase ahead
//     (hides under exp2+P-write+PV). q for all 4 slabs prefetched pre-barrier.
// Verified fragment layouts (learn_hip m89/m91/m92/m120), v_mfma_f32_16x16x32_bf16:
//   A: lane holds A[m=lane&15][k=(lane>>4)*8 + j], j=0..7
//   B: lane holds B[k=(lane>>4)*8 + j][n=lane&15]
//   C/D: col = lane&15, row = (lane>>4)*4 + reg

typedef unsigned short u16;
typedef unsigned int   u32;
typedef __attribute__((ext_vector_type(8))) __bf16 bf16x8;
typedef __attribute__((ext_vector_type(4))) float  f32x4;
typedef __attribute__((ext_vector_type(4))) u16    u16x4;

#define DEV __device__ __forceinline__

#define LOG2E 1.4426950408889634f

DEV float bf2f(u16 s) {
    u32 u = ((u32)s) << 16;
    float f;
    __builtin_memcpy(&f, &u, 4);
    return f;
}
DEV u16 f2bf(float f) {
    __bf16 h = (__bf16)f;              // native RNE convert (m240: don't hand-roll)
    u16 u;
    __builtin_memcpy(&u, &h, 2);
    return u;
}

// async global->LDS, 16 B per lane; LDS dest wave-uniform base + lane*16
#define GLD_LDS16(gp, lp)                                                           \
    __builtin_amdgcn_global_load_lds(                                               \
        (const __attribute__((address_space(1))) u32*)(const void*)(gp),            \
        (__attribute__((address_space(3))) u32*)(void*)(lp), 16, 0, 0)

// ---------------------------------------------------------------- transpose W (fp32 -> bf16)
// WT[1024][256]: rows 0-255 Wq^T, 256-511 Wk^T, 512-767 Wv^T, 768-1023 Wgate^T
// WfT[256][256] = Wfinal^T
__global__ void k_transpose(const float* __restrict__ Wq, const float* __restrict__ Wk,
                            const float* __restrict__ Wv, const float* __restrict__ Wg,
                            const float* __restrict__ Wf,
                            u16* __restrict__ WT, u16* __restrict__ WfT) {
    int idx = blockIdx.x * 256 + threadIdx.x;
    if (idx < 1024 * 256) {
        int gcol = idx >> 8, p = idx & 255;
        int sel = gcol >> 8, c = gcol & 255;
        const float* W = sel == 0 ? Wq : sel == 1 ? Wk : sel == 2 ? Wv : Wg;
        WT[idx] = f2bf(W[p * 256 + c]);
    } else {
        int j = idx - 1024 * 256;            // [0, 65536)
        int d = j >> 8, hc = j & 255;
        WfT[j] = f2bf(Wf[hc * 256 + d]);
    }
}

// ---------------------------------------------------------------- LayerNorm 1
// x1d [32768][256] fp32 -> x1 [32768][256] bf16.  One wave per row.
__global__ __launch_bounds__(256) void k_ln1(const float* __restrict__ x,
                                             const float* __restrict__ gg,
                                             const float* __restrict__ bb,
                                             u16* __restrict__ y) {
    int lane = threadIdx.x & 63, wave = threadIdx.x >> 6;
    int row = blockIdx.x * 4 + wave;
    float4 xv = *(const float4*)(x + row * 256 + lane * 4);
    float v0 = xv.x, v1 = xv.y, v2 = xv.z, v3 = xv.w;
    float s  = v0 + v1 + v2 + v3;
    float s2 = v0*v0 + v1*v1 + v2*v2 + v3*v3;
    #pragma unroll
    for (int msk = 32; msk; msk >>= 1) {
        s  += __shfl_xor(s,  msk, 64);
        s2 += __shfl_xor(s2, msk, 64);
    }
    float mu  = s * (1.0f / 256.0f);
    float var = s2 * (1.0f / 256.0f) - mu * mu;
    float rs  = rsqrtf(var + 1e-5f);
    float4 gv = *(const float4*)(gg + lane * 4);
    float4 bv = *(const float4*)(bb + lane * 4);
    ushort4 o;
    o.x = f2bf((v0 - mu) * rs * gv.x + bv.x);
    o.y = f2bf((v1 - mu) * rs * gv.y + bv.y);
    o.z = f2bf((v2 - mu) * rs * gv.z + bv.z);
    o.w = f2bf((v3 - mu) * rs * gv.w + bv.w);
    *(ushort4*)(y + row * 256 + lane * 4) = o;
}

// ---------------------------------------------------------------- LN2 + pair bias
// x2d [65536][128] fp32 -> biasT[h][j][i] fp32, PRE-SCALED by log2e
// (biasT[h*65536 + j*256 + i]; transposed so k_attn loads float4 over i)
__global__ __launch_bounds__(256) void k_ln2bias(const float* __restrict__ x2,
                                                 const float* __restrict__ gg,
                                                 const float* __restrict__ bb,
                                                 const float* __restrict__ W2d,
                                                 float* __restrict__ biasT) {
    int lane = threadIdx.x & 63, wave = threadIdx.x >> 6;
    int b = blockIdx.x;
    int i = (b >> 8) * 4 + wave;                     // [0,256)
    int j = b & 255;                                 // [0,256)
    int row = i * 256 + j;
    float2 xv = *(const float2*)(x2 + row * 128 + lane * 2);
    float v0 = xv.x, v1 = xv.y;
    float s = v0 + v1, s2 = v0*v0 + v1*v1;
    #pragma unroll
    for (int msk = 32; msk; msk >>= 1) {
        s  += __shfl_xor(s,  msk, 64);
        s2 += __shfl_xor(s2, msk, 64);
    }
    float mu  = s * (1.0f / 128.0f);
    float var = s2 * (1.0f / 128.0f) - mu * mu;
    float rs  = rsqrtf(var + 1e-5f);
    float2 gv = *(const float2*)(gg + lane * 2);
    float2 bv = *(const float2*)(bb + lane * 2);
    float xn0 = (v0 - mu) * rs * gv.x + bv.x;
    float xn1 = (v1 - mu) * rs * gv.y + bv.y;
    int p0 = lane * 2;
    float4 w0a = *(const float4*)(W2d + p0 * 8);
    float4 w0b = *(const float4*)(W2d + p0 * 8 + 4);
    float4 w1a = *(const float4*)(W2d + (p0 + 1) * 8);
    float4 w1b = *(const float4*)(W2d + (p0 + 1) * 8 + 4);
    float p[8];
    p[0] = xn0 * w0a.x + xn1 * w1a.x;
    p[1] = xn0 * w0a.y + xn1 * w1a.y;
    p[2] = xn0 * w0a.z + xn1 * w1a.z;
    p[3] = xn0 * w0a.w + xn1 * w1a.w;
    p[4] = xn0 * w0b.x + xn1 * w1b.x;
    p[5] = xn0 * w0b.y + xn1 * w1b.y;
    p[6] = xn0 * w0b.z + xn1 * w1b.z;
    p[7] = xn0 * w0b.w + xn1 * w1b.w;
    #pragma unroll
    for (int hh = 0; hh < 8; hh++)
        #pragma unroll
        for (int msk = 32; msk; msk >>= 1)
            p[hh] += __shfl_xor(p[hh], msk, 64);
    if (lane == 0) {
        #pragma unroll
        for (int hh = 0; hh < 8; hh++)
            biasT[hh * 65536 + j * 256 + i] = p[hh] * LOG2E;
    }
}

// ---------------------------------------------------------------- staged 128x128 GEMM core
// C[128x128 tile] = X[rowbase..+127][0..K) * WTb[colbase..+127][0..K)^T
// As/Bs: [128][64] u16, chunk-swizzled: phys chunk p of row r holds logical
// chunk p ^ (r&7)  (chunk = 8 u16 = 16 B).  BK=64, 2-barrier K-loop.
DEV void gemm128_core(const u16* __restrict__ X, const u16* __restrict__ WTb,
                      int rowbase, int colbase, int K,
                      u16* As, u16* Bs, f32x4 acc[4][4], int lane, int wave) {
    int l8 = lane & 7, r8 = lane >> 3;       // chunk-in-row, row-in-segment (8 rows/instr)
    int gchunk = l8 ^ (r8 & 7);              // xor swizzle: phys chunk l8 <- logical chunk l8^r8
    int lrow = lane & 15, quad = lane >> 4;
    int wr = (wave >> 1) * 64, wc = (wave & 1) * 64;

    for (int kk = 0; kk < K; kk += 64) {
        #pragma unroll
        for (int i = 0; i < 4; i++) {
            int s = wave * 4 + i;                            // segment 0..15 (8 rows each)
            const u16* g = X + (rowbase + s * 8 + r8) * K + kk + gchunk * 8;
            GLD_LDS16(g, As + s * 512);
        }
        #pragma unroll
        for (int i = 0; i < 4; i++) {
            int s = wave * 4 + i;
            const u16* g = WTb + (colbase + s * 8 + r8) * K + kk + gchunk * 8;
            GLD_LDS16(g, Bs + s * 512);
        }
        __syncthreads();                                     // waits vmcnt(0) for the DMA
        #pragma unroll
        for (int k2 = 0; k2 < 64; k2 += 32) {
            int cidx = (k2 >> 3) + quad;                     // logical chunk 0..7
            bf16x8 af[4], bf[4];
            #pragma unroll
            for (int t = 0; t < 4; t++) {
                int R = wr + t * 16 + lrow;
                af[t] = *(const bf16x8*)(As + R * 64 + ((cidx ^ (R & 7)) << 3));
            }
            #pragma unroll
            for (int t = 0; t < 4; t++) {
                int R = wc + t * 16 + lrow;
                bf[t] = *(const bf16x8*)(Bs + R * 64 + ((cidx ^ (R & 7)) << 3));
            }
            #pragma unroll
            for (int i = 0; i < 4; i++)
                #pragma unroll
                for (int j = 0; j < 4; j++)
                    acc[i][j] = __builtin_amdgcn_mfma_f32_16x16x32_bf16(af[i], bf[j], acc[i][j], 0, 0, 0);
        }
        __syncthreads();
    }
}

// ---------------------------------------------------------------- QKVG projection
// X=x1 [32768][256] @ WT -> cols 0-255 q (scaled by log2e/sqrt(C)), 256-511 k,
// 512-767 v (stored transposed vt[m][o][i]), 768-1023 gate (sigmoid applied,
// stored transposed gT[m][o][i]).
// grid (256, 8), block 256.  Block tile 128x128, wave tile 64x64.
__global__ __launch_bounds__(256) void k_qkvg(const u16* __restrict__ X, const u16* __restrict__ WT,
                                              u16* __restrict__ q, u16* __restrict__ kb,
                                              u16* __restrict__ vt, u16* __restrict__ gt,
                                              const float* __restrict__ bgate) {
    __shared__ u16 As[128 * 64];
    __shared__ u16 Bs[128 * 64];
    int lane = threadIdx.x & 63, wave = threadIdx.x >> 6;
    int rowbase = blockIdx.x * 128;
    int colbase = blockIdx.y * 128;
    f32x4 acc[4][4];
    #pragma unroll
    for (int i = 0; i < 4; i++)
        #pragma unroll
        for (int j = 0; j < 4; j++)
            acc[i][j] = (f32x4){0.f, 0.f, 0.f, 0.f};
    gemm128_core(X, WT, rowbase, colbase, 256, As, Bs, acc, lane, wave);
    int lrow = lane & 15, quad = lane >> 4;
    int wrb = rowbase + (wave >> 1) * 64, wcb = colbase + (wave & 1) * 64;
    int which = blockIdx.y >> 1;          // uniform per block: 0=q 1=k 2=v 3=gate
    #pragma unroll
    for (int it = 0; it < 4; it++)
        #pragma unroll
        for (int jt = 0; jt < 4; jt++) {
            int grow0 = wrb + it * 16 + quad * 4;      // +r stays in same 256-row band
            int gcol  = wcb + jt * 16 + lrow;
            int o = gcol & 255;
            if (which == 0) {
                #pragma unroll
                for (int r = 0; r < 4; r++)
                    q[(grow0 + r) * 256 + o] = f2bf(acc[it][jt][r] * (0.17677669529663687f * LOG2E));
            } else if (which == 1) {
                #pragma unroll
                for (int r = 0; r < 4; r++)
                    kb[(grow0 + r) * 256 + o] = f2bf(acc[it][jt][r]);
            } else if (which == 2) {
                int mm = grow0 >> 8, ii = grow0 & 255;
                ushort4 pv;
                pv.x = f2bf(acc[it][jt][0]);
                pv.y = f2bf(acc[it][jt][1]);
                pv.z = f2bf(acc[it][jt][2]);
                pv.w = f2bf(acc[it][jt][3]);
                *(ushort4*)(vt + (mm * 256 + o) * 256 + ii) = pv;
            } else {
                int mm = grow0 >> 8, ii = grow0 & 255;
                float bgo = bgate[o];
                ushort4 pv;
                pv.x = f2bf(1.0f / (1.0f + __expf(-(acc[it][jt][0] + bgo))));
                pv.y = f2bf(1.0f / (1.0f + __expf(-(acc[it][jt][1] + bgo))));
                pv.z = f2bf(1.0f / (1.0f + __expf(-(acc[it][jt][2] + bgo))));
                pv.w = f2bf(1.0f / (1.0f + __expf(-(acc[it][jt][3] + bgo))));
                *(ushort4*)(gt + (mm * 256 + o) * 256 + ii) = pv;
            }
        }
}

// ---------------------------------------------------------------- attention
// grid (m=128, h=8), block 256 (4 waves).  K AND V staged ONCE per block (LDS,
// R9-verified swizzles).  Each wave: 4 slabs x 2 half-phases of 128 j.
// LDS map (u16 idx):
//   Vs [0,8192):      V [32 o][256 ii], phys chunk = c ^ (o&7)        (c = ii>>3)
//   Ks [8192,16384):  K [256 j][32 cc], phys chunk = quad ^ ((j>>1)&3)
//   P  [16384,25088): per-wave padded [16][136]  (half-size: 128 j per phase)
// 50176 B -> 3 blocks/CU.  bias bbuf[8] in regs as QK^T C-operand, prefetched
// one phase ahead (hides under exp2 + P-write + PV).  q[0..3] pre-barrier.
__global__ __launch_bounds__(256, 3) void k_attn(const u16* __restrict__ q, const u16* __restrict__ kb,
                                                 const u16* __restrict__ vt, const u16* __restrict__ gt,
                                                 const float* __restrict__ biasT,
                                                 u16* __restrict__ tmp) {
    __shared__ u16 S[25088];               // 50176 B
    u16* Vs = S;
    u16* Ks = S + 8192;
    int lane = threadIdx.x & 63, wave = threadIdx.x >> 6;
    int lrow = lane & 15, quad = lane >> 4, lk = quad * 8;
    int m = blockIdx.x, h = blockIdx.y;

    const u16* qm  = q  + m * 65536 + h * 32;
    const u16* kbm = kb + m * 65536 + h * 32;
    const u16* vtm = vt + (m * 256 + h * 32) * 256;
    const u16* gtm = gt + (m * 256 + h * 32) * 256;
    u16*       tm  = tmp + m * 65536 + h * 32;
    const float* bh = biasT + h * 65536;
    u16* Pw = S + 16384 + wave * 2176;     // [16][136]

    // ---- q prefetch for all 4 slabs (overlaps K/V DMA + barrier)
    bf16x8 aq[4];
    #pragma unroll
    for (int s = 0; s < 4; s++)
        aq[s] = *(const bf16x8*)(qm + (s * 64 + wave * 16 + lrow) * 256 + lk);

    // ---- bulk DMA stage (R9-verified): K segs waves 0-1, V segs waves 2-3
    if (wave < 2) {
        int jl = lane >> 2;
        int qq = (lane & 3) ^ ((lane >> 3) & 3);
        const u16* gK = kbm + jl * 256 + qq * 8;
        #pragma unroll
        for (int t = 0; t < 8; t++) {
            int seg = wave * 8 + t;
            GLD_LDS16(gK + seg * 4096, Ks + seg * 512);
        }
    } else {
        int ol = lane >> 5;
        #pragma unroll
        for (int t = 0; t < 8; t++) {
            int seg = (wave - 2) * 8 + t;
            int cc = (lane & 31) ^ ((2 * t + ol) & 7);
            const u16* gV = vtm + (seg * 2 + ol) * 256 + cc * 8;
            GLD_LDS16(gV, Vs + seg * 512);
        }
    }

    // ---- bias phase-0 prefetch (slab 0, half 0) - overlaps DMA drain
    const float* bptr = bh + lrow * 256 + wave * 16 + quad * 4;
    f32x4 bbuf[8];
    #pragma unroll
    for (int jt = 0; jt < 8; jt++)
        bbuf[jt] = *(const f32x4*)(bptr + jt * 4096);

    __syncthreads();                                     // drains DMA (vmcnt 0)

    bf16x8 ones;
    {
        u16 ou = 0x3F80;                   // bf16 1.0
        __bf16 ob;
        __builtin_memcpy(&ob, &ou, 2);
        #pragma unroll
        for (int j = 0; j < 8; j++) ones[j] = ob;
    }

    #pragma unroll
    for (int s = 0; s < 4; s++) {
        int i0 = s * 64 + wave * 16;

        // gate prefetch (used at slab epilogue; hides under both halves)
        u16x4 gv4[2];
        #pragma unroll
        for (int ct = 0; ct < 2; ct++)
            gv4[ct] = *(const u16x4*)(gtm + (ct * 16 + lrow) * 256 + i0 + quad * 4);

        f32x4 oacc[2] = {{0.f,0.f,0.f,0.f}, {0.f,0.f,0.f,0.f}};
        f32x4 osum = {0.f, 0.f, 0.f, 0.f};

        #pragma unroll
        for (int h2 = 0; h2 < 2; h2++) {
            // ---- QK^T half (8 tiles), bias as C-operand from registers
            f32x4 acc[8];
            #pragma unroll
            for (int jt = 0; jt < 8; jt++) {
                int jg = h2 * 8 + jt;
                int ra = (jg * 16 + lrow) * 32 + ((quad ^ ((lrow >> 1) & 3)) << 3);
                bf16x8 bk = *(const bf16x8*)(Ks + ra);
                acc[jt] = __builtin_amdgcn_mfma_f32_16x16x32_bf16(aq[s], bk, bbuf[jt], 0, 0, 0);
            }

            // ---- prefetch bias for next phase (bbuf dead after QK^T above;
            //      hides under exp2 + P-write + PV below)
            int p = s * 2 + h2;
            if (p < 7) {
                int sn = (p + 1) >> 1, hn = (p + 1) & 1;
                const float* bp = bptr + hn * 32768 + sn * 64;
                #pragma unroll
                for (int jt = 0; jt < 8; jt++)
                    bbuf[jt] = *(const f32x4*)(bp + jt * 4096);
            }

            // ---- exp2 + P write (padded [16][136]; no max: LN-bounded)
            #pragma unroll
            for (int jt = 0; jt < 8; jt++)
                #pragma unroll
                for (int r = 0; r < 4; r++)
                    Pw[(quad * 4 + r) * 136 + jt * 16 + lrow] = f2bf(exp2f(acc[jt][r]));

            // ---- PV + ones-sum over this half's 128 j (all LDS operands)
            #pragma unroll
            for (int kk2 = 0; kk2 < 128; kk2 += 32) {
                bf16x8 ap = *(const bf16x8*)(Pw + lrow * 136 + kk2 + lk);
                osum = __builtin_amdgcn_mfma_f32_16x16x32_bf16(ap, ones, osum, 0, 0, 0);
                int c0 = ((h2 * 128 + kk2) >> 3) + quad;
                #pragma unroll
                for (int ct = 0; ct < 2; ct++) {
                    int o = ct * 16 + lrow;
                    bf16x8 bv = *(const bf16x8*)(Vs + o * 256 + ((c0 ^ (o & 7)) << 3));
                    oacc[ct] = __builtin_amdgcn_mfma_f32_16x16x32_bf16(ap, bv, oacc[ct], 0, 0, 0);
                }
            }
        }

        // ---- 1/sum + gate multiply + store gated output [m,i,h,c]
        float rinv[4];
        #pragma unroll
        for (int r = 0; r < 4; r++)
            rinv[r] = __builtin_amdgcn_rcpf(osum[r]);
        #pragma unroll
        for (int ct = 0; ct < 2; ct++)
            #pragma unroll
            for (int r = 0; r < 4; r++) {
                int i = i0 + quad * 4 + r;
                float gv = bf2f(gv4[ct][r]);
                tm[i * 256 + ct * 16 + lrow] = f2bf(oacc[ct][r] * rinv[r] * gv);
            }
    }
}

// ---------------------------------------------------------------- final projection
// tmp [32768][256] @ WfT + bfinal -> out FP32.  grid (256, 2).
__global__ __launch_bounds__(256) void k_final(const u16* __restrict__ T, const u16* __restrict__ WfT,
                                               const float* __restrict__ bfinal, float* __restrict__ out) {
    __shared__ u16 As[128 * 64];
    __shared__ u16 Bs[128 * 64];
    int lane = threadIdx.x & 63, wave = threadIdx.x >> 6;
    int rowbase = blockIdx.x * 128;
    int colbase = blockIdx.y * 128;
    f32x4 acc[4][4];
    #pragma unroll
    for (int i = 0; i < 4; i++)
        #pragma unroll
        for (int j = 0; j < 4; j++)
            acc[i][j] = (f32x4){0.f, 0.f, 0.f, 0.f};
    gemm128_core(T, WfT, rowbase, colbase, 256, As, Bs, acc, lane, wave);
    int lrow = lane & 15, quad = lane >> 4;
    int wrb = rowbase + (wave >> 1) * 64, wcb = colbase + (wave & 1) * 64;
    #pragma unroll
    for (int it = 0; it < 4; it++)
        #pragma unroll
        for (int jt = 0; jt < 4; jt++)
            #pragma unroll
            for (int r = 0; r < 4; r++) {
                int grow = wrb + it * 16 + quad * 4 + r;
                int gcol = wcb + jt * 16 + lrow;
                out[grow * 256 + gcol] = acc[it][jt][r] + bfinal[gcol];
            }
}

// ---------------------------------------------------------------- launch
extern "C" void kernel_launch(void* const* d_in, const int* in_sizes, int n_in,
                              void* d_out, int out_size, void* d_ws, size_t ws_size,
                              hipStream_t stream) {
    const float* x1d   = (const float*)d_in[0];
    const float* x2d   = (const float*)d_in[1];
    const float* ln1_g = (const float*)d_in[2];
    const float* ln1_b = (const float*)d_in[3];
    const float* ln2_g = (const float*)d_in[4];
    const float* ln2_b = (const float*)d_in[5];
    const float* Wq    = (const float*)d_in[6];
    const float* Wk    = (const float*)d_in[7];
    const float* Wv    = (const float*)d_in[8];
    const float* W2d   = (const float*)d_in[9];
    const float* Wg    = (const float*)d_in[10];
    const float* bg    = (const float*)d_in[11];
    const float* Wf    = (const float*)d_in[12];
    const float* bfin  = (const float*)d_in[13];
    float* out = (float*)d_out;

    char* ws = (char*)d_ws;
    u16*   x1   = (u16*)(ws);                    // 16,777,216 B  (reused as tmp)
    u16*   WT   = (u16*)(ws + 16777216);         //    524,288 B
    u16*   WfT  = (u16*)(ws + 17301504);         //    131,072 B
    float* bias = (float*)(ws + 17432576);       //  2,097,152 B  (biasT[h][j][i], log2e-scaled)
    u16*   qb   = (u16*)(ws + 19529728);         // 16,777,216 B
    u16*   kb   = (u16*)(ws + 36306944);         // 16,777,216 B
    u16*   vtb  = (u16*)(ws + 53084160);         // 16,777,216 B
    u16*   gb   = (u16*)(ws + 69861376);         // 16,777,216 B  (end: 86,638,592)
    u16*   tmp  = x1;                            // x1 dead after k_qkvg

    k_transpose<<<1280, 256, 0, stream>>>(Wq, Wk, Wv, Wg, Wf, WT, WfT);
    k_ln1<<<8192, 256, 0, stream>>>(x1d, ln1_g, ln1_b, x1);
    k_ln2bias<<<16384, 256, 0, stream>>>(x2d, ln2_g, ln2_b, W2d, bias);
    k_qkvg<<<dim3(256, 8), 256, 0, stream>>>(x1, WT, qb, kb, vtb, gb, bg);
    k_attn<<<dim3(128, 8), 256, 0, stream>>>(qb, kb, vtb, gb, bias, tmp);
    k_final<<<dim3(256, 2), 256, 0, stream>>>(tmp, WfT, bfin, out);
}